// Round 10
// baseline (45.374 us; speedup 1.0000x reference)
//
#include <hip/hip_runtime.h>

#define Bn 4
#define Sn 512
#define Hn 128
#define ST 4   // s-rows per softpv block

__device__ __forceinline__ float fast_exp2(float x) { return __builtin_amdgcn_exp2f(x); }
__device__ __forceinline__ float fast_rcp(float x)  { return __builtin_amdgcn_rcpf(x); }

#define C2 2.8853900817779268f   // 2*log2(e)

// Kernel 1: eq[b][s][h] = exp2(C2*(q@Wq^T + bias)) ; ekT[b][h][t] = exp2(C2*(k@Wk^T))
__global__ __launch_bounds__(256) void proj_kernel(
    const float* __restrict__ query, const float* __restrict__ key,
    const float* __restrict__ attn_W, const float* __restrict__ attn_b,
    float* __restrict__ eq, float* __restrict__ ekT)
{
    __shared__ float rows[2][4][Hn];       // 4 KB
    const int row0 = blockIdx.x * 4;       // global (b*S+s) row
    const int b    = row0 / Sn;
    const int t0   = row0 % Sn;            // multiple of 4
    const int tid  = threadIdx.x;

    {   // 2*4*128 floats = 256 float4, one per thread
        int src = tid >> 7, r = (tid >> 5) & 3, c4 = tid & 31;
        ((float4*)rows)[tid] =
            reinterpret_cast<const float4*>(src ? key : query)[(row0 + r) * 32 + c4];
    }
    __syncthreads();

    const int o     = tid & 127;
    const int which = tid >> 7;            // 0 = q-proj, 1 = k-proj (wave-uniform)
    float acc[4] = {0,0,0,0};
    const float* wrow = attn_W + o * (2 * Hn) + which * Hn;
    for (int c = 0; c < Hn; c += 4) {
        float4 wv = *reinterpret_cast<const float4*>(wrow + c);
        #pragma unroll
        for (int r = 0; r < 4; r++) {
            float4 rv = *reinterpret_cast<const float4*>(&rows[which][r][c]); // b128 broadcast
            acc[r] += rv.x * wv.x + rv.y * wv.y + rv.z * wv.z + rv.w * wv.w;
        }
    }
    if (which == 0) {
        float bias = attn_b[o];
        #pragma unroll
        for (int r = 0; r < 4; r++)
            eq[(row0 + r) * Hn + o] = fast_exp2(C2 * (acc[r] + bias));
    } else {
        float4 ev;
        ev.x = fast_exp2(C2 * acc[0]); ev.y = fast_exp2(C2 * acc[1]);
        ev.z = fast_exp2(C2 * acc[2]); ev.w = fast_exp2(C2 * acc[3]);
        *reinterpret_cast<float4*>(&ekT[(size_t)(b * Hn + o) * Sn + t0]) = ev;
    }
}

// Kernel 2: partial logits, fully LDS-resident inner loop.
// grid (32 s-tiles, Bn, 4 t-quarters * 2 h-halves) = 1024 blocks x 256 threads
// -> 4 blocks/CU, 4 waves/SIMD.  thread = (sg in 8, tc in 32) owning 2s x 4t x 64h.
// One cooperative stage: ek tile [64h][128t] (32 KB) + q pairs (4 KB) + w (256 B).
// Inner loop: 1 ds_read_b128 (ek) + 1 ds_read_b64 (q) + 1 ds_read_b32 (w)
// feeding 8 rcp + 16 fma.  No global traffic after the barrier.
__global__ __launch_bounds__(256) void score_kernel(
    const float* __restrict__ eq, const float* __restrict__ ekT,
    const float* __restrict__ v_w, float* __restrict__ pl)
{
    __shared__ float  ekL[64][128];  // 32 KB
    __shared__ float2 qs2[8][64];    // 4 KB: [sg][h] = eq rows (s0b+sg*2, +1) at hb+h
    __shared__ float  ws[64];        // -2 * v_w[hb+h]

    const int b   = blockIdx.y;
    const int s0b = blockIdx.x * 16;
    const int tq  = blockIdx.z >> 1;
    const int hh  = blockIdx.z & 1;
    const int hb  = hh * 64;
    const int tid = threadIdx.x;
    const int tc  = tid & 31;
    const int sg  = tid >> 5;
    const int t0  = tq * 128;

    // stage ek tile: 64 rows x 128 floats = 2048 float4, 8 per thread (coalesced)
    {
        const float* ksrc = ekT + ((size_t)b * Hn + hb) * Sn + t0;
        #pragma unroll
        for (int r = 0; r < 8; r++) {
            int idx = tid + r * 256;           // float4 index
            int row = idx >> 5, c4 = idx & 31;
            *reinterpret_cast<float4*>(&ekL[row][c4 * 4]) =
                *reinterpret_cast<const float4*>(ksrc + (size_t)row * Sn + c4 * 4);
        }
    }
    // stage q transposed into pairs: qs2[isg][h][sl] = eq[b][s0b+isg*2+sl][hb+h]
    for (int i = tid; i < 1024; i += 256) {
        int isg = i >> 7, sl = (i >> 6) & 1, h = i & 63;
        ((float*)&qs2[isg][h])[sl] =
            eq[(size_t)(b * Sn + s0b + isg * 2 + sl) * Hn + hb + h];
    }
    if (tid < 64) ws[tid] = -2.0f * v_w[hb + tid];
    __syncthreads();

    float4 A0 = {0,0,0,0}, A1 = {0,0,0,0};
    #pragma unroll 8
    for (int h = 0; h < 64; h++) {
        float4 e  = *reinterpret_cast<const float4*>(&ekL[h][tc * 4]); // 512B/half-wave
        float2 q2 = qs2[sg][h];      // ds_read_b64, broadcast (2 addrs/wave)
        float  w  = ws[h];           // ds_read_b32, broadcast
        A0.x += w * fast_rcp(q2.x * e.x + 1.f);
        A0.y += w * fast_rcp(q2.x * e.y + 1.f);
        A0.z += w * fast_rcp(q2.x * e.z + 1.f);
        A0.w += w * fast_rcp(q2.x * e.w + 1.f);
        A1.x += w * fast_rcp(q2.y * e.x + 1.f);
        A1.y += w * fast_rcp(q2.y * e.y + 1.f);
        A1.z += w * fast_rcp(q2.y * e.z + 1.f);
        A1.w += w * fast_rcp(q2.y * e.w + 1.f);
    }

    float* dst = pl + (((size_t)hh * Bn + b) * Sn + (s0b + sg * 2)) * Sn + t0 + tc * 4;
    *reinterpret_cast<float4*>(dst)      = A0;
    *reinterpret_cast<float4*>(dst + Sn) = A1;
}

// Kernel 3: softmax (summing the 2 h-half strips) + PV.  512 threads, grid (Sn/ST, Bn).
__global__ __launch_bounds__(512) void softpv_kernel(
    const float* __restrict__ value, const float* __restrict__ pl,
    float* __restrict__ out, float* __restrict__ out_w)
{
    __shared__ float4 scT4[Sn];               // weights transposed  8 KB
    __shared__ float4 part4[16][ST][Hn / 4];  // PV partials        32 KB

    const int b   = blockIdx.y;
    const int s0  = blockIdx.x * ST;
    const int tid = threadIdx.x;
    const int wave = tid >> 6, lane = tid & 63;

    if (wave < ST) {
        const int sr = wave;
        const float* r0 = pl + ((size_t)(0 * Bn + b) * Sn + (s0 + sr)) * Sn;
        const float* r1 = pl + ((size_t)(1 * Bn + b) * Sn + (s0 + sr)) * Sn;
        float v[8]; float m = -1e30f;
        #pragma unroll
        for (int i = 0; i < 8; i++) {
            v[i] = r0[lane + i * 64] + r1[lane + i * 64];
            m = fmaxf(m, v[i]);
        }
        #pragma unroll
        for (int off = 32; off; off >>= 1) m = fmaxf(m, __shfl_xor(m, off, 64));
        float sum = 0.f;
        const float l2e = 1.4426950408889634f;
        #pragma unroll
        for (int i = 0; i < 8; i++) { v[i] = fast_exp2((v[i] - m) * l2e); sum += v[i]; }
        #pragma unroll
        for (int off = 32; off; off >>= 1) sum += __shfl_xor(sum, off, 64);
        float inv = 1.0f / sum;
        float* wrow_out = out_w + (size_t)(b * Sn + s0 + sr) * Sn;
        #pragma unroll
        for (int i = 0; i < 8; i++) {
            float wgt = v[i] * inv;
            wrow_out[lane + i * 64] = wgt;             // normalized weights out
            ((float*)&scT4[lane + i * 64])[sr] = wgt;  // transposed copy for PV
        }
    }
    __syncthreads();

    // PV: thread = (tg in 16, hq in 32); value read once per block
    {
        const int hq = tid & 31, tg = tid >> 5;
        const float* vb = value + ((size_t)b * Sn + tg * 32) * Hn + hq * 4;
        float4 A0 = {0,0,0,0}, A1 = {0,0,0,0}, A2 = {0,0,0,0}, A3 = {0,0,0,0};
        #pragma unroll 4
        for (int i = 0; i < 32; i++) {
            float4 v4 = *reinterpret_cast<const float4*>(vb + i * Hn);
            float4 w4 = scT4[tg * 32 + i];     // b128 broadcast
            A0.x += w4.x * v4.x; A0.y += w4.x * v4.y; A0.z += w4.x * v4.z; A0.w += w4.x * v4.w;
            A1.x += w4.y * v4.x; A1.y += w4.y * v4.y; A1.z += w4.y * v4.z; A1.w += w4.y * v4.w;
            A2.x += w4.z * v4.x; A2.y += w4.z * v4.y; A2.z += w4.z * v4.z; A2.w += w4.z * v4.w;
            A3.x += w4.w * v4.x; A3.y += w4.w * v4.y; A3.z += w4.w * v4.z; A3.w += w4.w * v4.w;
        }
        part4[tg][0][hq] = A0;
        part4[tg][1][hq] = A1;
        part4[tg][2][hq] = A2;
        part4[tg][3][hq] = A3;
    }
    __syncthreads();
    {
        const int sg = tid >> 7, h = tid & 127;
        float r = 0.f;
        #pragma unroll
        for (int tg = 0; tg < 16; tg++)
            r += ((const float*)&part4[tg][sg][h >> 2])[h & 3];
        out[(b * Sn + s0 + sg) * Hn + h] = r;
    }
}

extern "C" void kernel_launch(void* const* d_in, const int* in_sizes, int n_in,
                              void* d_out, int out_size, void* d_ws, size_t ws_size,
                              hipStream_t stream) {
    const float* query  = (const float*)d_in[0];
    const float* key    = (const float*)d_in[1];
    const float* value  = (const float*)d_in[2];
    const float* attn_W = (const float*)d_in[3];
    const float* attn_b = (const float*)d_in[4];
    const float* v_w    = (const float*)d_in[5];

    float* out   = (float*)d_out;            // (B,S,H) then (B,S,S), both f32
    float* out_w = out + Bn * Sn * Hn;

    float* eq  = (float*)d_ws;               // B*S*H floats = 1 MB
    float* ekT = eq + Bn * Sn * Hn;          // B*H*S floats = 1 MB
    float* pl  = ekT + Bn * Hn * Sn;         // 2*B*S*S floats = 8 MB

    proj_kernel<<<Bn * Sn / 4, 256, 0, stream>>>(query, key, attn_W, attn_b, eq, ekT);
    score_kernel<<<dim3(32, Bn, 8), 256, 0, stream>>>(eq, ekT, v_w, pl);
    softpv_kernel<<<dim3(Sn / ST, Bn), 512, 0, stream>>>(value, pl, out, out_w);
}

// Round 11
// 40.335 us; speedup vs baseline: 1.1249x; 1.1249x over previous
//
#include <hip/hip_runtime.h>

#define Bn 4
#define Sn 512
#define Hn 128
#define ST 4   // s-rows per softpv block

__device__ __forceinline__ float fast_exp2(float x) { return __builtin_amdgcn_exp2f(x); }
__device__ __forceinline__ float fast_rcp(float x)  { return __builtin_amdgcn_rcpf(x); }

#define C2 2.8853900817779268f   // 2*log2(e)

// Kernel 1: eq[b][s][h] = exp2(C2*(q@Wq^T + bias)) ; ekT[b][h][t] = exp2(C2*(k@Wk^T))
__global__ __launch_bounds__(256) void proj_kernel(
    const float* __restrict__ query, const float* __restrict__ key,
    const float* __restrict__ attn_W, const float* __restrict__ attn_b,
    float* __restrict__ eq, float* __restrict__ ekT)
{
    __shared__ float rows[2][4][Hn];       // 4 KB
    const int row0 = blockIdx.x * 4;       // global (b*S+s) row
    const int b    = row0 / Sn;
    const int t0   = row0 % Sn;            // multiple of 4
    const int tid  = threadIdx.x;

    {   // 2*4*128 floats = 256 float4, one per thread
        int src = tid >> 7, r = (tid >> 5) & 3, c4 = tid & 31;
        ((float4*)rows)[tid] =
            reinterpret_cast<const float4*>(src ? key : query)[(row0 + r) * 32 + c4];
    }
    __syncthreads();

    const int o     = tid & 127;
    const int which = tid >> 7;            // 0 = q-proj, 1 = k-proj (wave-uniform)
    float acc[4] = {0,0,0,0};
    const float* wrow = attn_W + o * (2 * Hn) + which * Hn;
    for (int c = 0; c < Hn; c += 4) {
        float4 wv = *reinterpret_cast<const float4*>(wrow + c);
        #pragma unroll
        for (int r = 0; r < 4; r++) {
            float4 rv = *reinterpret_cast<const float4*>(&rows[which][r][c]); // b128 broadcast
            acc[r] += rv.x * wv.x + rv.y * wv.y + rv.z * wv.z + rv.w * wv.w;
        }
    }
    if (which == 0) {
        float bias = attn_b[o];
        #pragma unroll
        for (int r = 0; r < 4; r++)
            eq[(row0 + r) * Hn + o] = fast_exp2(C2 * (acc[r] + bias));
    } else {
        float4 ev;
        ev.x = fast_exp2(C2 * acc[0]); ev.y = fast_exp2(C2 * acc[1]);
        ev.z = fast_exp2(C2 * acc[2]); ev.w = fast_exp2(C2 * acc[3]);
        *reinterpret_cast<float4*>(&ekT[(size_t)(b * Hn + o) * Sn + t0]) = ev;
    }
}

// 4-way sigmoid combine: acc += sum_i w_i / (1 + q_i*c_i)   (one rcp per 4 terms)
__device__ __forceinline__ void comb4(float& acc, float4 q,
                                      float c0, float c1, float c2, float c3,
                                      float4 w) {
    float D0 = fmaf(q.x, c0, 1.0f);
    float D1 = fmaf(q.y, c1, 1.0f);
    float D2 = fmaf(q.z, c2, 1.0f);
    float D3 = fmaf(q.w, c3, 1.0f);
    float P01 = D0 * D1, P23 = D2 * D3;
    float n01 = fmaf(w.y, D0, w.x * D1);
    float n23 = fmaf(w.w, D2, w.z * D3);
    float N   = fmaf(n01, P23, n23 * P01);
    acc = fmaf(N, fast_rcp(P01 * P23), acc);
}

// Kernel 2: partial logits, LDS-resident, 4-way-combined rcp.
// grid (32 s-tiles, Bn, 4 t-quarters * 2 h-halves) = 1024 blocks x 256 threads
// -> 4 blocks/CU, 4 waves/SIMD.  thread = (sg in 8, tc in 32) owning 2s x 4t x 64h.
// Per 4-h step: 4 ds_read_b128 (ek rows) + 3 b128 broadcasts (qA,qB,w)
// feeding 8 x (14 VALU + 1 rcp) for 32 elements.
__global__ __launch_bounds__(256) void score_kernel(
    const float* __restrict__ eq, const float* __restrict__ ekT,
    const float* __restrict__ v_w, float* __restrict__ pl)
{
    __shared__ float  ekL[64][128];  // 32 KB
    __shared__ float4 qsA[8][16];    // 2 KB: q row (s0b+sg*2+0), 4 h per entry
    __shared__ float4 qsB[8][16];    // 2 KB: q row (s0b+sg*2+1)
    __shared__ float4 ws4[16];       // -2*v_w, 4 h per entry

    const int b   = blockIdx.y;
    const int s0b = blockIdx.x * 16;
    const int tq  = blockIdx.z >> 1;
    const int hh  = blockIdx.z & 1;
    const int hb  = hh * 64;
    const int tid = threadIdx.x;
    const int tc  = tid & 31;
    const int sg  = tid >> 5;
    const int t0  = tq * 128;

    // stage ek tile: 64 rows x 128 floats = 2048 float4, 8 per thread (coalesced)
    {
        const float* ksrc = ekT + ((size_t)b * Hn + hb) * Sn + t0;
        #pragma unroll
        for (int r = 0; r < 8; r++) {
            int idx = tid + r * 256;           // float4 index
            int row = idx >> 5, c4 = idx & 31;
            *reinterpret_cast<float4*>(&ekL[row][c4 * 4]) =
                *reinterpret_cast<const float4*>(ksrc + (size_t)row * Sn + c4 * 4);
        }
    }
    // stage q rows as float4-per-4h: one float4 per thread
    {
        int sl = tid >> 7, rem = tid & 127, isg = rem >> 4, h4 = rem & 15;
        float4 v = *reinterpret_cast<const float4*>(
            eq + (size_t)(b * Sn + s0b + isg * 2 + sl) * Hn + hb + h4 * 4);
        (sl ? qsB : qsA)[isg][h4] = v;
    }
    if (tid < 16) {
        float4 wv = *reinterpret_cast<const float4*>(v_w + hb + tid * 4);
        float4 w2; w2.x = -2.f * wv.x; w2.y = -2.f * wv.y;
        w2.z = -2.f * wv.z; w2.w = -2.f * wv.w;
        ws4[tid] = w2;
    }
    __syncthreads();

    float4 A0 = {0,0,0,0}, A1 = {0,0,0,0};
    #pragma unroll 4
    for (int h4 = 0; h4 < 16; h4++) {
        const int h = h4 * 4;
        float4 e0 = *reinterpret_cast<const float4*>(&ekL[h + 0][tc * 4]);
        float4 e1 = *reinterpret_cast<const float4*>(&ekL[h + 1][tc * 4]);
        float4 e2 = *reinterpret_cast<const float4*>(&ekL[h + 2][tc * 4]);
        float4 e3 = *reinterpret_cast<const float4*>(&ekL[h + 3][tc * 4]);
        float4 qa = qsA[sg][h4];     // b128 broadcast
        float4 qb = qsB[sg][h4];
        float4 w  = ws4[h4];
        comb4(A0.x, qa, e0.x, e1.x, e2.x, e3.x, w);
        comb4(A0.y, qa, e0.y, e1.y, e2.y, e3.y, w);
        comb4(A0.z, qa, e0.z, e1.z, e2.z, e3.z, w);
        comb4(A0.w, qa, e0.w, e1.w, e2.w, e3.w, w);
        comb4(A1.x, qb, e0.x, e1.x, e2.x, e3.x, w);
        comb4(A1.y, qb, e0.y, e1.y, e2.y, e3.y, w);
        comb4(A1.z, qb, e0.z, e1.z, e2.z, e3.z, w);
        comb4(A1.w, qb, e0.w, e1.w, e2.w, e3.w, w);
    }

    float* dst = pl + (((size_t)hh * Bn + b) * Sn + (s0b + sg * 2)) * Sn + t0 + tc * 4;
    *reinterpret_cast<float4*>(dst)      = A0;
    *reinterpret_cast<float4*>(dst + Sn) = A1;
}

// Kernel 3: softmax (summing the 2 h-half strips) + PV.  512 threads, grid (Sn/ST, Bn).
__global__ __launch_bounds__(512) void softpv_kernel(
    const float* __restrict__ value, const float* __restrict__ pl,
    float* __restrict__ out, float* __restrict__ out_w)
{
    __shared__ float4 scT4[Sn];               // weights transposed  8 KB
    __shared__ float4 part4[16][ST][Hn / 4];  // PV partials        32 KB

    const int b   = blockIdx.y;
    const int s0  = blockIdx.x * ST;
    const int tid = threadIdx.x;
    const int wave = tid >> 6, lane = tid & 63;

    if (wave < ST) {
        const int sr = wave;
        const float* r0 = pl + ((size_t)(0 * Bn + b) * Sn + (s0 + sr)) * Sn;
        const float* r1 = pl + ((size_t)(1 * Bn + b) * Sn + (s0 + sr)) * Sn;
        float v[8]; float m = -1e30f;
        #pragma unroll
        for (int i = 0; i < 8; i++) {
            v[i] = r0[lane + i * 64] + r1[lane + i * 64];
            m = fmaxf(m, v[i]);
        }
        #pragma unroll
        for (int off = 32; off; off >>= 1) m = fmaxf(m, __shfl_xor(m, off, 64));
        float sum = 0.f;
        const float l2e = 1.4426950408889634f;
        #pragma unroll
        for (int i = 0; i < 8; i++) { v[i] = fast_exp2((v[i] - m) * l2e); sum += v[i]; }
        #pragma unroll
        for (int off = 32; off; off >>= 1) sum += __shfl_xor(sum, off, 64);
        float inv = 1.0f / sum;
        float* wrow_out = out_w + (size_t)(b * Sn + s0 + sr) * Sn;
        #pragma unroll
        for (int i = 0; i < 8; i++) {
            float wgt = v[i] * inv;
            wrow_out[lane + i * 64] = wgt;             // normalized weights out
            ((float*)&scT4[lane + i * 64])[sr] = wgt;  // transposed copy for PV
        }
    }
    __syncthreads();

    // PV: thread = (tg in 16, hq in 32); value read once per block
    {
        const int hq = tid & 31, tg = tid >> 5;
        const float* vb = value + ((size_t)b * Sn + tg * 32) * Hn + hq * 4;
        float4 A0 = {0,0,0,0}, A1 = {0,0,0,0}, A2 = {0,0,0,0}, A3 = {0,0,0,0};
        #pragma unroll 4
        for (int i = 0; i < 32; i++) {
            float4 v4 = *reinterpret_cast<const float4*>(vb + i * Hn);
            float4 w4 = scT4[tg * 32 + i];     // b128 broadcast
            A0.x += w4.x * v4.x; A0.y += w4.x * v4.y; A0.z += w4.x * v4.z; A0.w += w4.x * v4.w;
            A1.x += w4.y * v4.x; A1.y += w4.y * v4.y; A1.z += w4.y * v4.z; A1.w += w4.y * v4.w;
            A2.x += w4.z * v4.x; A2.y += w4.z * v4.y; A2.z += w4.z * v4.z; A2.w += w4.z * v4.w;
            A3.x += w4.w * v4.x; A3.y += w4.w * v4.y; A3.z += w4.w * v4.z; A3.w += w4.w * v4.w;
        }
        part4[tg][0][hq] = A0;
        part4[tg][1][hq] = A1;
        part4[tg][2][hq] = A2;
        part4[tg][3][hq] = A3;
    }
    __syncthreads();
    {
        const int sg = tid >> 7, h = tid & 127;
        float r = 0.f;
        #pragma unroll
        for (int tg = 0; tg < 16; tg++)
            r += ((const float*)&part4[tg][sg][h >> 2])[h & 3];
        out[(b * Sn + s0 + sg) * Hn + h] = r;
    }
}

extern "C" void kernel_launch(void* const* d_in, const int* in_sizes, int n_in,
                              void* d_out, int out_size, void* d_ws, size_t ws_size,
                              hipStream_t stream) {
    const float* query  = (const float*)d_in[0];
    const float* key    = (const float*)d_in[1];
    const float* value  = (const float*)d_in[2];
    const float* attn_W = (const float*)d_in[3];
    const float* attn_b = (const float*)d_in[4];
    const float* v_w    = (const float*)d_in[5];

    float* out   = (float*)d_out;            // (B,S,H) then (B,S,S), both f32
    float* out_w = out + Bn * Sn * Hn;

    float* eq  = (float*)d_ws;               // B*S*H floats = 1 MB
    float* ekT = eq + Bn * Sn * Hn;          // B*H*S floats = 1 MB
    float* pl  = ekT + Bn * Hn * Sn;         // 2*B*S*S floats = 8 MB

    proj_kernel<<<Bn * Sn / 4, 256, 0, stream>>>(query, key, attn_W, attn_b, eq, ekT);
    score_kernel<<<dim3(32, Bn, 8), 256, 0, stream>>>(eq, ekT, v_w, pl);
    softpv_kernel<<<dim3(Sn / ST, Bn), 512, 0, stream>>>(value, pl, out, out_w);
}